// Round 8
// baseline (1082.041 us; speedup 1.0000x reference)
//
#include <hip/hip_runtime.h>
#include <float.h>

#define NPTS  8192
#define FDIM  512
#define NB    2
#define TK    12
#define KNN   8
#define NQ    4             // column quarters

typedef __attribute__((ext_vector_type(8))) short short8;   // 8 bf16 (4 VGPRs)
typedef __attribute__((ext_vector_type(4))) float floatx4;  // MFMA C/D

// ---------------- fp32 -> bf16 (RNE)
__device__ __forceinline__ unsigned f2bf(float x) {
    unsigned u = __float_as_uint(x);
    return (u + 0x7FFFu + ((u >> 16) & 1u)) >> 16;
}

// ---------------- fused: patch extraction + bf16 cast + scaled norms
__global__ void extract_prep_kernel(const float* __restrict__ img, float* __restrict__ feats,
                                    ushort* __restrict__ bf, float* __restrict__ sqc16) {
    __shared__ float part[4];
    const int tid = threadIdx.x;
    int t = blockIdx.x * 256 + tid;   // float4 index; block covers 2 rows (128 f4 each)
    int fq = t & 127;
    int p  = (t >> 7) & 8191;
    int b  = t >> 20;
    int f = fq << 2;
    int d = f & 7;
    int w = (f >> 3) & 7;
    int h = f >> 6;
    int db = p & 7, wb = (p >> 3) & 31, hb = p >> 8;
    size_t src = (((size_t)(b * 256 + hb * 8 + h)) * 256 + (size_t)(wb * 8 + w)) * 64
               + (size_t)(db * 8 + d);
    float4 v = *(const float4*)(img + src);
    *(float4*)(feats + ((size_t)t << 2)) = v;
    uint2 wv;
    wv.x = f2bf(v.x) | (f2bf(v.y) << 16);
    wv.y = f2bf(v.z) | (f2bf(v.w) << 16);
    *(uint2*)(bf + ((size_t)t << 2)) = wv;
    float s = v.x * v.x + v.y * v.y + v.z * v.z + v.w * v.w;
#pragma unroll
    for (int off = 32; off > 0; off >>= 1) s += __shfl_xor(s, off);
    if ((tid & 63) == 0) part[tid >> 6] = s;
    __syncthreads();
    if (tid < 2) {
        int gw = blockIdx.x * 2 + tid;
        sqc16[gw] = (part[2 * tid] + part[2 * tid + 1]) * 16.f + 24576.f;
    }
}

// packed-key sorted top-12 insert (key = d16<<16 | col  -> ties pick smaller col)
__device__ __forceinline__ void insert12(unsigned* L, unsigned key) {
#pragma unroll
    for (int p = TK - 1; p > 0; --p) {
        bool bp = key < L[p - 1];
        bool bc = key < L[p];
        L[p] = bp ? L[p - 1] : (bc ? key : L[p]);
    }
    L[0] = (key < L[0]) ? key : L[0];
}

__device__ __forceinline__ unsigned pkminu16(unsigned a, unsigned b) {
    unsigned d;
    asm("v_pk_min_u16 %0, %1, %2" : "=v"(d) : "v"(a), "v"(b));
    return d;
}

__device__ __forceinline__ void gl_lds16(const ushort* g, ushort* l) {
    __builtin_amdgcn_global_load_lds(
        (const __attribute__((address_space(1))) unsigned int*)g,
        (__attribute__((address_space(3))) unsigned int*)l, 16, 0, 0);
}

// ---------------- MFMA bf16 Gram, BK=64 (64 MFMA per barrier-pair), 4-phase epilogue
// grid (64 rowblocks, NB, 4 col-quarters), 256 threads. Block: rows 128, cols 2048.
__global__ __launch_bounds__(256, 2)
void knn_mfma(const ushort* __restrict__ bfeats, const float* __restrict__ sqc16,
              unsigned* __restrict__ cand) {
    __shared__ __align__(16) ushort As[128 * 64];    // 16 KB [row][64k], 8x16B groups XOR-swz
    __shared__ __align__(16) ushort Bs[256 * 64];    // 32 KB [col][64k]
    __shared__ __align__(16) ushort Sc[32 * 264];    // 16.9 KB scores, stride 264

    const int row0 = blockIdx.x * 128;
    const int b    = blockIdx.y;
    const int quarter = blockIdx.z;
    const ushort* bfb = bfeats + (size_t)b * NPTS * FDIM;
    const float*  sqg = sqc16 + b * NPTS;

    const int tid  = threadIdx.x;
    const int wid  = tid >> 6;
    const int lane = tid & 63;
    const int l15  = lane & 15;
    const int q    = lane >> 4;
    const int wr   = wid & 1;    // row 64-half of the wave
    const int wc   = wid >> 1;   // col 128-half of the wave
    const int h8   = l15 & 7;    // 3-bit row swizzle key

    // staging: 8 lanes per 128B row, 16B group XOR-swizzled by row-in-chunk
    const int srl8 = lane >> 3;                 // row within 8-row chunk
    const int sg8  = (lane & 7) ^ srl8;         // global 16B group to fetch

    // row/col base terms for fragment reads (ushort units, 64/row)
    int rowA[4], rowB[8];
#pragma unroll
    for (int rf = 0; rf < 4; ++rf) rowA[rf] = (wr * 64 + rf * 16 + l15) << 6;
#pragma unroll
    for (int cf = 0; cf < 8; ++cf) rowB[cf] = (wc * 128 + cf * 16 + l15) << 6;

    unsigned L[4][TK];
#pragma unroll
    for (int h = 0; h < 4; ++h)
#pragma unroll
        for (int s = 0; s < TK; ++s) L[h][s] = 0xFFFFFFFFu;

    const int srow = tid >> 3;      // selection: 8 threads per score-row (32 rows)
    const int scp  = tid & 7;       // each scans 32 cols

    for (int ct = 0; ct < 8; ++ct) {
        const int colb = quarter * 2048 + ct * 256;

        float sqv[8];
#pragma unroll
        for (int cf = 0; cf < 8; ++cf) sqv[cf] = sqg[colb + wc * 128 + cf * 16 + l15];

        floatx4 acc[4][8];
#pragma unroll
        for (int rf = 0; rf < 4; ++rf)
#pragma unroll
            for (int cf = 0; cf < 8; ++cf) acc[rf][cf] = (floatx4)0.f;

        for (int kt = 0; kt < 8; ++kt) {
            const int kb = kt * 64;
            __syncthreads();
#pragma unroll
            for (int p = 0; p < 4; ++p) {
                int rg = wid * 4 + p;    // 16 chunks x 8 rows = 128 rows
                gl_lds16(bfb + (size_t)(row0 + rg * 8 + srl8) * FDIM + kb + sg8 * 8,
                         &As[rg * 512]);
            }
#pragma unroll
            for (int p = 0; p < 8; ++p) {
                int cg = wid * 8 + p;    // 32 chunks x 8 rows = 256 cols
                gl_lds16(bfb + (size_t)(colb + cg * 8 + srl8) * FDIM + kb + sg8 * 8,
                         &Bs[cg * 512]);
            }
            __syncthreads();

#pragma unroll
            for (int ks = 0; ks < 2; ++ks) {
                const int gsw = (((ks << 2) + q) ^ h8) << 3;
                short8 av[4], bv[8];
#pragma unroll
                for (int rf = 0; rf < 4; ++rf) av[rf] = *(const short8*)&As[rowA[rf] + gsw];
#pragma unroll
                for (int cf = 0; cf < 8; ++cf) bv[cf] = *(const short8*)&Bs[rowB[cf] + gsw];
#pragma unroll
                for (int rf = 0; rf < 4; ++rf)
#pragma unroll
                    for (int cf = 0; cf < 8; ++cf)
                        acc[rf][cf] = __builtin_amdgcn_mfma_f32_16x16x32_bf16(
                            av[rf], bv[cf], acc[rf][cf], 0, 0, 0);
            }
        }

        // epilogue: four 32-row phases (Sc holds 32 rows)
#pragma unroll
        for (int hr = 0; hr < 4; ++hr) {
            __syncthreads();
            if (wr == (hr >> 1)) {
#pragma unroll
                for (int rr = 0; rr < 2; ++rr) {
                    const int rf = (hr & 1) * 2 + rr;
#pragma unroll
                    for (int cf = 0; cf < 8; ++cf) {
                        const int ctl = wc * 128 + cf * 16 + l15;
                        const int gcol = colb + ctl;
#pragma unroll
                        for (int v = 0; v < 4; ++v) {
                            const int rbuf = rr * 16 + q * 4 + v;
                            const int grow = row0 + hr * 32 + rbuf;
                            float s = fmaf(-32.f, acc[rf][cf][v], sqv[cf]);
                            s = fminf(fmaxf(s, 0.f), 65535.f);
                            ushort us = (grow == gcol) ? (ushort)65535 : (ushort)s;
                            Sc[rbuf * 264 + ctl] = us;
                        }
                    }
                }
            }
            __syncthreads();
            const ushort* base = &Sc[srow * 264 + scp * 32];
            const int colg0 = colb + scp * 32;
            unsigned* Lp = L[hr];
#pragma unroll
            for (int j = 0; j < 4; ++j) {
                uint4 w = *(const uint4*)(base + j * 8);
                unsigned m = pkminu16(pkminu16(w.x, w.y), pkminu16(w.z, w.w));
                unsigned mm = min(m & 0xFFFFu, m >> 16);
                unsigned thr = Lp[TK - 1] >> 16;
                if (mm <= thr) {
                    const int c0 = colg0 + j * 8;
                    unsigned k;
                    k = (w.x << 16) | (unsigned)(c0 + 0); if (k < Lp[TK-1]) insert12(Lp, k);
                    k = (w.x & 0xFFFF0000u) | (unsigned)(c0 + 1); if (k < Lp[TK-1]) insert12(Lp, k);
                    k = (w.y << 16) | (unsigned)(c0 + 2); if (k < Lp[TK-1]) insert12(Lp, k);
                    k = (w.y & 0xFFFF0000u) | (unsigned)(c0 + 3); if (k < Lp[TK-1]) insert12(Lp, k);
                    k = (w.z << 16) | (unsigned)(c0 + 4); if (k < Lp[TK-1]) insert12(Lp, k);
                    k = (w.z & 0xFFFF0000u) | (unsigned)(c0 + 5); if (k < Lp[TK-1]) insert12(Lp, k);
                    k = (w.w << 16) | (unsigned)(c0 + 6); if (k < Lp[TK-1]) insert12(Lp, k);
                    k = (w.w & 0xFFFF0000u) | (unsigned)(c0 + 7); if (k < Lp[TK-1]) insert12(Lp, k);
                }
            }
        }
    }

    // merge the 8 scanners of each row (butterfly, snapshot-then-insert; same wave)
#pragma unroll
    for (int m = 1; m <= 4; m <<= 1) {
#pragma unroll
        for (int h = 0; h < 4; ++h) {
            unsigned o[TK];
#pragma unroll
            for (int s = 0; s < TK; ++s) o[s] = (unsigned)__shfl_xor((int)L[h][s], m);
#pragma unroll
            for (int s = 0; s < TK; ++s)
                if (o[s] < L[h][TK - 1]) insert12(L[h], o[s]);
        }
    }

    if (scp == 0) {
#pragma unroll
        for (int h = 0; h < 4; ++h) {
            const int grow = row0 + h * 32 + srow;
            unsigned* dst = cand + ((size_t)(b * NQ + quarter) * NPTS + grow) * TK;
#pragma unroll
            for (int s = 0; s < TK; ++s) dst[s] = L[h][s];
        }
    }
}

// ---------------- merge 4x12 keys -> top-12, fp64 exact re-rank, adjacency scatter
__global__ void refine_kernel(const float* __restrict__ feats, const unsigned* __restrict__ cand,
                              float* __restrict__ adj) {
    __shared__ unsigned scols[4][TK];
    const int wv   = threadIdx.x >> 6;
    const int lane = threadIdx.x & 63;
    const int gw = blockIdx.x * 4 + wv;             // 0..16383
    const int b = gw >> 13;
    const int r = gw & (NPTS - 1);

    unsigned key = 0xFFFFFFFFu;
    if (lane < NQ * TK) {
        int qf = lane / TK, s = lane % TK;
        key = cand[((size_t)(b * NQ + qf) * NPTS + r) * TK + s];
    }
    int rank = 0;
#pragma unroll
    for (int u = 0; u < NQ * TK; ++u) {
        unsigned ku = (unsigned)__shfl((int)key, u);
        rank += (ku < key) ? 1 : 0;
    }
    if (lane < NQ * TK && rank < TK) scols[wv][rank] = key & 0xFFFFu;
    __syncthreads();

    const float* fb = feats + (size_t)b * NPTS * FDIM;
    const float* fr = fb + (size_t)r * FDIM + lane * 8;
    float* adjb = adj + (size_t)b * NPTS * NPTS;

    float4 a0 = *(const float4*)fr;
    float4 a1 = *(const float4*)(fr + 4);

    double dist[TK];
    // batch gathers in groups of 4 to break the load->reduce latency chain
#pragma unroll
    for (int g = 0; g < TK / 4; ++g) {
        float4 c0[4], c1[4];
#pragma unroll
        for (int i = 0; i < 4; ++i) {
            int c = (int)scols[wv][g * 4 + i];
            const float* fc = fb + (size_t)c * FDIM + lane * 8;
            c0[i] = *(const float4*)fc;
            c1[i] = *(const float4*)(fc + 4);
        }
#pragma unroll
        for (int i = 0; i < 4; ++i) {
            double sm = 0.0, e;
            e = (double)a0.x - (double)c0[i].x; sm += e * e;
            e = (double)a0.y - (double)c0[i].y; sm += e * e;
            e = (double)a0.z - (double)c0[i].z; sm += e * e;
            e = (double)a0.w - (double)c0[i].w; sm += e * e;
            e = (double)a1.x - (double)c1[i].x; sm += e * e;
            e = (double)a1.y - (double)c1[i].y; sm += e * e;
            e = (double)a1.z - (double)c1[i].z; sm += e * e;
            e = (double)a1.w - (double)c1[i].w; sm += e * e;
#pragma unroll
            for (int off = 32; off > 0; off >>= 1) sm += __shfl_xor(sm, off);
            dist[g * 4 + i] = sm;
        }
    }

    if (lane < TK) {
        const int t = lane;
        const int ct = (int)scols[wv][t];
        int rk = 0;
#pragma unroll
        for (int u = 0; u < TK; ++u) {
            int cu = (int)scols[wv][u];
            rk += (dist[u] < dist[t]) || (dist[u] == dist[t] && cu < ct);
        }
        if (rk < KNN) {
            atomicAdd(&adjb[(size_t)r * NPTS + ct], 0.5f);
            atomicAdd(&adjb[(size_t)ct * NPTS + r], 0.5f);
        }
    }
}

extern "C" void kernel_launch(void* const* d_in, const int* in_sizes, int n_in,
                              void* d_out, int out_size, void* d_ws, size_t ws_size,
                              hipStream_t stream) {
    (void)in_sizes; (void)n_in; (void)out_size; (void)ws_size;
    const float* img = (const float*)d_in[0];

    float* feats = (float*)d_out;                               // 2*8192*512
    float* adj   = feats + (size_t)NB * NPTS * FDIM;            // 2*8192*8192

    float*    sqc16 = (float*)d_ws;                             // 16384 floats
    unsigned* cand  = (unsigned*)((char*)d_ws + 65536);         // 16384*4*12 u32 (~3.1 MB)
    ushort*   bfeat = (ushort*)adj;  // bf16 feats staged in adj region (wiped by memset later)

    extract_prep_kernel<<<8192, 256, 0, stream>>>(img, feats, bfeat, sqc16);
    knn_mfma      <<<dim3(NPTS / 128, NB, NQ), 256, 0, stream>>>(bfeat, sqc16, cand);
    (void)hipMemsetAsync(adj, 0, (size_t)NB * NPTS * NPTS * sizeof(float), stream);
    refine_kernel <<<(NB * NPTS) / 4, 256, 0, stream>>>(feats, cand, adj);
}

// Round 9
// 884.309 us; speedup vs baseline: 1.2236x; 1.2236x over previous
//
#include <hip/hip_runtime.h>
#include <float.h>

#define NPTS  8192
#define FDIM  512
#define NB    2
#define TK    12
#define KNN   8
#define NQ    4             // column quarters

typedef __attribute__((ext_vector_type(8))) short short8;   // 8 bf16 (4 VGPRs)
typedef __attribute__((ext_vector_type(4))) float floatx4;  // MFMA C/D

// ---------------- fp32 -> bf16 (RNE)
__device__ __forceinline__ unsigned f2bf(float x) {
    unsigned u = __float_as_uint(x);
    return (u + 0x7FFFu + ((u >> 16) & 1u)) >> 16;
}

// ---------------- fused: patch extraction + bf16 cast + scaled norms
__global__ void extract_prep_kernel(const float* __restrict__ img, float* __restrict__ feats,
                                    ushort* __restrict__ bf, float* __restrict__ sqc16) {
    __shared__ float part[4];
    const int tid = threadIdx.x;
    int t = blockIdx.x * 256 + tid;   // float4 index; block covers 2 rows (128 f4 each)
    int fq = t & 127;
    int p  = (t >> 7) & 8191;
    int b  = t >> 20;
    int f = fq << 2;
    int d = f & 7;
    int w = (f >> 3) & 7;
    int h = f >> 6;
    int db = p & 7, wb = (p >> 3) & 31, hb = p >> 8;
    size_t src = (((size_t)(b * 256 + hb * 8 + h)) * 256 + (size_t)(wb * 8 + w)) * 64
               + (size_t)(db * 8 + d);
    float4 v = *(const float4*)(img + src);
    *(float4*)(feats + ((size_t)t << 2)) = v;
    uint2 wv;
    wv.x = f2bf(v.x) | (f2bf(v.y) << 16);
    wv.y = f2bf(v.z) | (f2bf(v.w) << 16);
    *(uint2*)(bf + ((size_t)t << 2)) = wv;
    float s = v.x * v.x + v.y * v.y + v.z * v.z + v.w * v.w;
#pragma unroll
    for (int off = 32; off > 0; off >>= 1) s += __shfl_xor(s, off);
    if ((tid & 63) == 0) part[tid >> 6] = s;
    __syncthreads();
    if (tid < 2) {
        int gw = blockIdx.x * 2 + tid;
        sqc16[gw] = (part[2 * tid] + part[2 * tid + 1]) * 16.f + 24576.f;
    }
}

// packed-key sorted top-12 insert (key = d16<<16 | col  -> ties pick smaller col)
__device__ __forceinline__ void insert12(unsigned* L, unsigned key) {
#pragma unroll
    for (int p = TK - 1; p > 0; --p) {
        bool bp = key < L[p - 1];
        bool bc = key < L[p];
        L[p] = bp ? L[p - 1] : (bc ? key : L[p]);
    }
    L[0] = (key < L[0]) ? key : L[0];
}

__device__ __forceinline__ int swz(int x) { return (x & 3) ^ ((x >> 2) & 3); }

__device__ __forceinline__ unsigned pkminu16(unsigned a, unsigned b) {
    unsigned d;
    asm("v_pk_min_u16 %0, %1, %2" : "=v"(d) : "v"(a), "v"(b));
    return d;
}

__device__ __forceinline__ void gl_lds16(const ushort* g, ushort* l) {
    __builtin_amdgcn_global_load_lds(
        (const __attribute__((address_space(1))) unsigned int*)g,
        (__attribute__((address_space(3))) unsigned int*)l, 16, 0, 0);
}

// ---------------- MFMA bf16 Gram (BK=32, round-7 structure: no spills) + fused adj zeroing
// grid (64 rowblocks, NB, 4 col-quarters), 256 threads. Block: rows 128, cols 2048.
// Each block also zeroes its 1/512 slice of adj (2 float4-stores per kt, hidden
// under the staging loads' vmcnt drain).
__global__ __launch_bounds__(256, 2)
void knn_mfma(const ushort* __restrict__ bfeats, const float* __restrict__ sqc16,
              unsigned* __restrict__ cand, float* __restrict__ adj) {
    __shared__ __align__(16) ushort As[128 * 32];    // 8 KB  [row][32k] swizzled 16B groups
    __shared__ __align__(16) ushort Bs[256 * 32];    // 16 KB [col][32k] swizzled
    __shared__ __align__(16) ushort Sc[64 * 264];    // 33.8 KB scores, stride 264

    const int row0 = blockIdx.x * 128;
    const int b    = blockIdx.y;
    const int quarter = blockIdx.z;
    const ushort* bfb = bfeats + (size_t)b * NPTS * FDIM;
    const float*  sqg = sqc16 + b * NPTS;

    const int tid  = threadIdx.x;
    const int wid  = tid >> 6;
    const int lane = tid & 63;
    const int l15  = lane & 15;
    const int q    = lane >> 4;
    const int wr   = wid & 1;    // row 64-half of the wave
    const int wc   = wid >> 1;   // col 128-half of the wave

    // adj-zero slice for this block: 65536 float4 (= 1/512 of adj)
    const int blin = blockIdx.x + 64 * (blockIdx.y + NB * blockIdx.z);
    float4* zbase = (float4*)adj + (size_t)blin * 65536;
    const float4 zero4 = {0.f, 0.f, 0.f, 0.f};

    // kstep-invariant fragment LDS offsets (ushort units); uniform-bank by swizzle
    const int fsw = (q ^ swz(l15)) << 3;
    int aoff[4], boff[8];
#pragma unroll
    for (int rf = 0; rf < 4; ++rf) aoff[rf] = ((wr * 64 + rf * 16 + l15) << 5) + fsw;
#pragma unroll
    for (int cf = 0; cf < 8; ++cf) boff[cf] = ((wc * 128 + cf * 16 + l15) << 5) + fsw;

    // staging decomposition: 4 lanes per 64B row-chunk, group XOR-swizzled
    const int srl = lane >> 2;                    // row/col within 16-group
    const int sg  = (lane & 3) ^ swz(srl);        // global 16B group to fetch

    unsigned L[2][TK];
#pragma unroll
    for (int h = 0; h < 2; ++h)
#pragma unroll
        for (int s = 0; s < TK; ++s) L[h][s] = 0xFFFFFFFFu;

    const int srow = tid >> 2;      // selection: 4 threads per score-row
    const int scp  = tid & 3;       // each scans 64 cols

    for (int ct = 0; ct < 8; ++ct) {
        const int colb = quarter * 2048 + ct * 256;

        float sqv[8];
#pragma unroll
        for (int cf = 0; cf < 8; ++cf) sqv[cf] = sqg[colb + wc * 128 + cf * 16 + l15];

        floatx4 acc[4][8];
#pragma unroll
        for (int rf = 0; rf < 4; ++rf)
#pragma unroll
            for (int cf = 0; cf < 8; ++cf) acc[rf][cf] = (floatx4)0.f;

        for (int kt = 0; kt < 16; ++kt) {
            const int kb = kt * 32;
            __syncthreads();
#pragma unroll
            for (int p = 0; p < 2; ++p) {
                int rg = wid * 2 + p;
                gl_lds16(bfb + (size_t)(row0 + rg * 16 + srl) * FDIM + kb + sg * 8,
                         &As[rg * 512]);
            }
#pragma unroll
            for (int p = 0; p < 4; ++p) {
                int cg = wid * 4 + p;
                gl_lds16(bfb + (size_t)(colb + cg * 16 + srl) * FDIM + kb + sg * 8,
                         &Bs[cg * 512]);
            }
            // adj zeroing: 2 coalesced float4 stores; drains with the staging loads
            {
                const int it = ct * 16 + kt;
                zbase[it * 512 + tid]       = zero4;
                zbase[it * 512 + 256 + tid] = zero4;
            }
            __syncthreads();

            short8 av[4], bv[8];
#pragma unroll
            for (int rf = 0; rf < 4; ++rf) av[rf] = *(const short8*)&As[aoff[rf]];
#pragma unroll
            for (int cf = 0; cf < 8; ++cf) bv[cf] = *(const short8*)&Bs[boff[cf]];
#pragma unroll
            for (int rf = 0; rf < 4; ++rf)
#pragma unroll
                for (int cf = 0; cf < 8; ++cf)
                    acc[rf][cf] = __builtin_amdgcn_mfma_f32_16x16x32_bf16(
                        av[rf], bv[cf], acc[rf][cf], 0, 0, 0);
        }

        // epilogue: two 64-row phases (Sc buffer holds 64 rows)
#pragma unroll
        for (int hr = 0; hr < 2; ++hr) {
            __syncthreads();
            if (wr == hr) {
#pragma unroll
                for (int rf = 0; rf < 4; ++rf)
#pragma unroll
                    for (int cf = 0; cf < 8; ++cf) {
                        const int ctl = wc * 128 + cf * 16 + l15;
                        const int gcol = colb + ctl;
#pragma unroll
                        for (int v = 0; v < 4; ++v) {
                            const int rbuf = rf * 16 + q * 4 + v;
                            const int grow = row0 + hr * 64 + rbuf;
                            float s = fmaf(-32.f, acc[rf][cf][v], sqv[cf]);
                            s = fminf(fmaxf(s, 0.f), 65535.f);
                            ushort us = (grow == gcol) ? (ushort)65535 : (ushort)s;
                            Sc[rbuf * 264 + ctl] = us;
                        }
                    }
            }
            __syncthreads();
            const ushort* base = &Sc[srow * 264 + scp * 64];
            const int colg0 = colb + scp * 64;
            unsigned* Lp = L[hr];
#pragma unroll
            for (int j = 0; j < 8; ++j) {
                uint4 w = *(const uint4*)(base + j * 8);
                unsigned m = pkminu16(pkminu16(w.x, w.y), pkminu16(w.z, w.w));
                unsigned mm = min(m & 0xFFFFu, m >> 16);
                unsigned thr = Lp[TK - 1] >> 16;
                if (mm <= thr) {
                    const int c0 = colg0 + j * 8;
                    unsigned k;
                    k = (w.x << 16) | (unsigned)(c0 + 0); if (k < Lp[TK-1]) insert12(Lp, k);
                    k = (w.x & 0xFFFF0000u) | (unsigned)(c0 + 1); if (k < Lp[TK-1]) insert12(Lp, k);
                    k = (w.y << 16) | (unsigned)(c0 + 2); if (k < Lp[TK-1]) insert12(Lp, k);
                    k = (w.y & 0xFFFF0000u) | (unsigned)(c0 + 3); if (k < Lp[TK-1]) insert12(Lp, k);
                    k = (w.z << 16) | (unsigned)(c0 + 4); if (k < Lp[TK-1]) insert12(Lp, k);
                    k = (w.z & 0xFFFF0000u) | (unsigned)(c0 + 5); if (k < Lp[TK-1]) insert12(Lp, k);
                    k = (w.w << 16) | (unsigned)(c0 + 6); if (k < Lp[TK-1]) insert12(Lp, k);
                    k = (w.w & 0xFFFF0000u) | (unsigned)(c0 + 7); if (k < Lp[TK-1]) insert12(Lp, k);
                }
            }
        }
    }

    // merge the 4 scanners of each row (butterfly, snapshot-then-insert)
#pragma unroll
    for (int m = 1; m <= 2; m <<= 1) {
#pragma unroll
        for (int h = 0; h < 2; ++h) {
            unsigned o[TK];
#pragma unroll
            for (int s = 0; s < TK; ++s) o[s] = (unsigned)__shfl_xor((int)L[h][s], m);
#pragma unroll
            for (int s = 0; s < TK; ++s)
                if (o[s] < L[h][TK - 1]) insert12(L[h], o[s]);
        }
    }

    if (scp == 0) {
#pragma unroll
        for (int h = 0; h < 2; ++h) {
            const int grow = row0 + h * 64 + srow;
            unsigned* dst = cand + ((size_t)(b * NQ + quarter) * NPTS + grow) * TK;
#pragma unroll
            for (int s = 0; s < TK; ++s) dst[s] = L[h][s];
        }
    }
}

// ---------------- merge 4x12 keys -> top-12, fp64 exact re-rank, adjacency scatter
__global__ void refine_kernel(const float* __restrict__ feats, const unsigned* __restrict__ cand,
                              float* __restrict__ adj) {
    __shared__ unsigned scols[4][TK];
    const int wv   = threadIdx.x >> 6;
    const int lane = threadIdx.x & 63;
    const int gw = blockIdx.x * 4 + wv;             // 0..16383
    const int b = gw >> 13;
    const int r = gw & (NPTS - 1);

    unsigned key = 0xFFFFFFFFu;
    if (lane < NQ * TK) {
        int qf = lane / TK, s = lane % TK;
        key = cand[((size_t)(b * NQ + qf) * NPTS + r) * TK + s];
    }
    int rank = 0;
#pragma unroll
    for (int u = 0; u < NQ * TK; ++u) {
        unsigned ku = (unsigned)__shfl((int)key, u);
        rank += (ku < key) ? 1 : 0;
    }
    if (lane < NQ * TK && rank < TK) scols[wv][rank] = key & 0xFFFFu;
    __syncthreads();

    const float* fb = feats + (size_t)b * NPTS * FDIM;
    const float* fr = fb + (size_t)r * FDIM + lane * 8;
    float* adjb = adj + (size_t)b * NPTS * NPTS;

    float4 a0 = *(const float4*)fr;
    float4 a1 = *(const float4*)(fr + 4);

    double dist[TK];
#pragma unroll
    for (int g = 0; g < TK / 4; ++g) {
        float4 c0[4], c1[4];
#pragma unroll
        for (int i = 0; i < 4; ++i) {
            int c = (int)scols[wv][g * 4 + i];
            const float* fc = fb + (size_t)c * FDIM + lane * 8;
            c0[i] = *(const float4*)fc;
            c1[i] = *(const float4*)(fc + 4);
        }
#pragma unroll
        for (int i = 0; i < 4; ++i) {
            double sm = 0.0, e;
            e = (double)a0.x - (double)c0[i].x; sm += e * e;
            e = (double)a0.y - (double)c0[i].y; sm += e * e;
            e = (double)a0.z - (double)c0[i].z; sm += e * e;
            e = (double)a0.w - (double)c0[i].w; sm += e * e;
            e = (double)a1.x - (double)c1[i].x; sm += e * e;
            e = (double)a1.y - (double)c1[i].y; sm += e * e;
            e = (double)a1.z - (double)c1[i].z; sm += e * e;
            e = (double)a1.w - (double)c1[i].w; sm += e * e;
#pragma unroll
            for (int off = 32; off > 0; off >>= 1) sm += __shfl_xor(sm, off);
            dist[g * 4 + i] = sm;
        }
    }

    if (lane < TK) {
        const int t = lane;
        const int ct = (int)scols[wv][t];
        int rk = 0;
#pragma unroll
        for (int u = 0; u < TK; ++u) {
            int cu = (int)scols[wv][u];
            rk += (dist[u] < dist[t]) || (dist[u] == dist[t] && cu < ct);
        }
        if (rk < KNN) {
            atomicAdd(&adjb[(size_t)r * NPTS + ct], 0.5f);
            atomicAdd(&adjb[(size_t)ct * NPTS + r], 0.5f);
        }
    }
}

extern "C" void kernel_launch(void* const* d_in, const int* in_sizes, int n_in,
                              void* d_out, int out_size, void* d_ws, size_t ws_size,
                              hipStream_t stream) {
    (void)in_sizes; (void)n_in; (void)out_size; (void)ws_size;
    const float* img = (const float*)d_in[0];

    float* feats = (float*)d_out;                               // 2*8192*512
    float* adj   = feats + (size_t)NB * NPTS * FDIM;            // 2*8192*8192

    float*    sqc16 = (float*)d_ws;                             // 16384 floats
    unsigned* cand  = (unsigned*)((char*)d_ws + 65536);         // 16384*4*12 u32 (~3.1 MB)
    ushort*   bfeat = (ushort*)((char*)d_ws + (16u << 20));     // bf16 feats (67 MB) in ws

    extract_prep_kernel<<<8192, 256, 0, stream>>>(img, feats, bfeat, sqc16);
    knn_mfma      <<<dim3(NPTS / 128, NB, NQ), 256, 0, stream>>>(bfeat, sqc16, cand, adj);
    refine_kernel <<<(NB * NPTS) / 4, 256, 0, stream>>>(feats, cand, adj);
}